// Round 1
// baseline (68.105 us; speedup 1.0000x reference)
//
#include <hip/hip_runtime.h>

#define SEQ 197
#define NP 196
#define NHEADS 12
#define CUT 98   // int(0.5 * 196)

// One block per batch. Computes attn[p] = sum_h x[b,h,0,1+p], then selects
// the top-98 patches by rank (stable tie-break on lower index, matching
// jax.lax.top_k), writing a 0/1 float mask [B,196] to workspace.
__global__ void attn_mask_kernel(const float* __restrict__ x,
                                 float* __restrict__ mask) {
    const int b = blockIdx.x;
    const int t = threadIdx.x;
    __shared__ float sA[NP];

    float a = 0.0f;
    if (t < NP) {
        const float* base = x + (size_t)b * NHEADS * SEQ * SEQ + 1 + t;
        #pragma unroll
        for (int h = 0; h < NHEADS; ++h) {
            a += base[(size_t)h * SEQ * SEQ];
        }
        sA[t] = a;
    }
    __syncthreads();

    if (t < NP) {
        int rank = 0;
        #pragma unroll 4
        for (int j = 0; j < NP; ++j) {
            float aj = sA[j];                 // uniform address -> LDS broadcast
            rank += (aj > a) || (aj == a && j < t);
        }
        mask[b * NP + t] = (rank < CUT) ? 1.0f : 0.0f;
    }
}

// Grid-stride over float4 pixels. img layout [B,3,224,224]; a 4-aligned group
// of 4 pixels never crosses a 16-pixel patch boundary -> one mask read/vec.
__global__ void apply_mask_kernel(const float* __restrict__ img,
                                  const float* __restrict__ mask,
                                  float* __restrict__ out, int nvec) {
    const int stride = gridDim.x * blockDim.x;
    for (int i = blockIdx.x * blockDim.x + threadIdx.x; i < nvec; i += stride) {
        int x4   = i % 56;        // float4 column within a 224-pixel row
        int rest = i / 56;
        int y    = rest % 224;
        int bc   = rest / 224;
        int b    = bc / 3;
        int patch = (y >> 4) * 14 + (x4 >> 2);   // (y/16)*14 + (x/16), x = 4*x4
        float m = mask[b * NP + patch];

        float4 v = reinterpret_cast<const float4*>(img)[i];
        v.x *= m; v.y *= m; v.z *= m; v.w *= m;
        reinterpret_cast<float4*>(out)[i] = v;
    }
}

extern "C" void kernel_launch(void* const* d_in, const int* in_sizes, int n_in,
                              void* d_out, int out_size, void* d_ws, size_t ws_size,
                              hipStream_t stream) {
    const float* x   = (const float*)d_in[0];   // [B, 12, 197, 197] fp32
    const float* img = (const float*)d_in[1];   // [B, 3, 224, 224] fp32
    float* out  = (float*)d_out;                // [B, 3*224*224] fp32
    float* mask = (float*)d_ws;                 // [B, 196] fp32 scratch

    const int B = in_sizes[0] / (NHEADS * SEQ * SEQ);   // 256

    attn_mask_kernel<<<B, 256, 0, stream>>>(x, mask);

    const int nvec = out_size / 4;              // float4 count = 9,633,792
    const int blocks = 2048;
    apply_mask_kernel<<<blocks, 256, 0, stream>>>(img, mask, out, nvec);
}

// Round 2
// 59.784 us; speedup vs baseline: 1.1392x; 1.1392x over previous
//
#include <hip/hip_runtime.h>

#define SEQ 197
#define NP 196
#define NHEADS 12
#define CUT 98                    // int(0.5 * 196)
#define VECS_PER_BATCH 37632      // 3*224*224/4 float4 per batch
#define BPB 8                     // blocks per batch
#define VECS_PER_BLOCK 4704       // 37632 / 8

typedef float f4 __attribute__((ext_vector_type(4)));

// Fused: each block (b = bid/8, j = bid%8) computes batch b's top-98 patch
// mask redundantly in LDS, then applies it to its 1/8 slice of the image.
__global__ __launch_bounds__(256) void fused_fixation_kernel(
        const float* __restrict__ x,
        const float* __restrict__ img,
        float* __restrict__ out) {
    const int bid = blockIdx.x;
    const int b = bid >> 3;       // batch index
    const int j = bid & 7;        // sub-block within batch
    const int t = threadIdx.x;

    __shared__ float sA[NP];
    __shared__ float sM[NP];

    // 1) head-summed CLS->patch attention (matches jnp.sum head order)
    float a = 0.0f;
    if (t < NP) {
        const float* base = x + (size_t)b * NHEADS * SEQ * SEQ + 1 + t;
        #pragma unroll
        for (int h = 0; h < NHEADS; ++h)
            a += base[(size_t)h * SEQ * SEQ];
        sA[t] = a;
    }
    __syncthreads();

    // 2) stable descending rank (ties -> lower index), matches lax.top_k
    if (t < NP) {
        int rank = 0;
        #pragma unroll 4
        for (int p = 0; p < NP; ++p) {
            float ap = sA[p];               // uniform LDS broadcast
            rank += (ap > a) || (ap == a && p < t);
        }
        sM[t] = (rank < CUT) ? 1.0f : 0.0f;
    }
    __syncthreads();

    // 3) stream this block's image slice: float4 in, non-temporal float4 out
    const f4* imgb = (const f4*)img + (size_t)b * VECS_PER_BATCH;
    f4*       outb = (f4*)out       + (size_t)b * VECS_PER_BATCH;

    const int vend = (j + 1) * VECS_PER_BLOCK;
    for (int v = j * VECS_PER_BLOCK + t; v < vend; v += 256) {
        int x4 = v % 56;                    // float4 col in a 224-px row
        int yy = (v / 56) % 224;            // pixel row (channel-independent)
        float m = sM[(yy >> 4) * 14 + (x4 >> 2)];
        f4 p = imgb[v];
        p *= m;
        __builtin_nontemporal_store(p, &outb[v]);
    }
}

extern "C" void kernel_launch(void* const* d_in, const int* in_sizes, int n_in,
                              void* d_out, int out_size, void* d_ws, size_t ws_size,
                              hipStream_t stream) {
    const float* x   = (const float*)d_in[0];   // [B, 12, 197, 197] fp32
    const float* img = (const float*)d_in[1];   // [B, 3, 224, 224] fp32
    float* out = (float*)d_out;                 // [B, 3*224*224] fp32

    const int B = in_sizes[0] / (NHEADS * SEQ * SEQ);   // 256

    fused_fixation_kernel<<<B * BPB, 256, 0, stream>>>(x, img, out);
}

// Round 3
// 49.398 us; speedup vs baseline: 1.3787x; 1.2103x over previous
//
#include <hip/hip_runtime.h>

#define SEQ 197
#define NP 196
#define NHEADS 12
#define CUT 98                    // int(0.5 * 196)
#define VECS_PER_BATCH 37632      // 3*224*224/4 float4 per batch
#define BPB 8                     // blocks per batch
#define VECS_PER_BLOCK 4704       // 37632 / 8

typedef float f4 __attribute__((ext_vector_type(4)));

// Fused: each block (b = bid&255, j = bid>>8) computes batch b's top-98 patch
// mask redundantly in LDS, then applies it to its 1/8 slice of the image.
// b = bid&255 puts a batch's 8 blocks on the SAME XCD (round-robin dispatch,
// 256 % 8 == 0) so the attention-row reads hit that XCD's L2 after the first.
// Loads are predicated on the mask: zero patches are never fetched from HBM.
__global__ __launch_bounds__(256) void fused_fixation_kernel(
        const float* __restrict__ x,
        const float* __restrict__ img,
        float* __restrict__ out) {
    const int bid = blockIdx.x;
    const int b = bid & 255;      // batch index
    const int j = bid >> 8;       // sub-block within batch
    const int t = threadIdx.x;

    __shared__ float sA[NP];
    __shared__ float sM[NP];

    // 1) head-summed CLS->patch attention (matches jnp.sum head order)
    float a = 0.0f;
    if (t < NP) {
        const float* base = x + (size_t)b * NHEADS * SEQ * SEQ + 1 + t;
        #pragma unroll
        for (int h = 0; h < NHEADS; ++h)
            a += base[(size_t)h * SEQ * SEQ];
        sA[t] = a;
    }
    __syncthreads();

    // 2) stable descending rank (ties -> lower index), matches lax.top_k
    if (t < NP) {
        int rank = 0;
        #pragma unroll 4
        for (int p = 0; p < NP; ++p) {
            float ap = sA[p];               // uniform LDS broadcast
            rank += (ap > a) || (ap == a && p < t);
        }
        sM[t] = (rank < CUT) ? 1.0f : 0.0f;
    }
    __syncthreads();

    // 3) stream this block's image slice: predicated float4 in, NT float4 out
    const f4* imgb = (const f4*)img + (size_t)b * VECS_PER_BATCH;
    f4*       outb = (f4*)out       + (size_t)b * VECS_PER_BATCH;

    const int vend = (j + 1) * VECS_PER_BLOCK;
    for (int v = j * VECS_PER_BLOCK + t; v < vend; v += 256) {
        int x4 = v % 56;                    // float4 col in a 224-px row
        int yy = (v / 56) % 224;            // pixel row (channel-independent)
        float m = sM[(yy >> 4) * 14 + (x4 >> 2)];
        f4 p = {0.0f, 0.0f, 0.0f, 0.0f};
        if (m != 0.0f)                      // exec-masked: zero patches never fetched
            p = imgb[v];
        __builtin_nontemporal_store(p, &outb[v]);
    }
}

extern "C" void kernel_launch(void* const* d_in, const int* in_sizes, int n_in,
                              void* d_out, int out_size, void* d_ws, size_t ws_size,
                              hipStream_t stream) {
    const float* x   = (const float*)d_in[0];   // [B, 12, 197, 197] fp32
    const float* img = (const float*)d_in[1];   // [B, 3, 224, 224] fp32
    float* out = (float*)d_out;                 // [B, 3*224*224] fp32

    const int B = in_sizes[0] / (NHEADS * SEQ * SEQ);   // 256

    fused_fixation_kernel<<<B * BPB, 256, 0, stream>>>(x, img, out);
}